// Round 1
// 343.640 us; speedup vs baseline: 1.0655x; 1.0655x over previous
//
#include <hip/hip_runtime.h>

// Round 8: r7 (244us rocprof) + non-draining per-step barrier (T4-style).
// Theory: __syncthreads() emits s_waitcnt vmcnt(0) before s_barrier every
// step, draining the global x-prefetch at the barrier (~300-600 cyc/step of
// exposed L3/HBM latency). Replace with raw s_barrier + lgkmcnt(0)-only
// wait so global loads stay in flight across barriers; prefetch depth = 2
// full steps via x2 loop unroll (named regs xpA/xpB, no runtime indexing).
// Also: compile-time acc extracts (kill per-lane dynamic vector indexing,
// ~40 VALU/step), fold xacc into first h-MFMA as C operand (save 16 movs).
// Everything else identical to r7: 256 blocks x 512 threads, 8 rows/block,
// dup-on-write M=16 tile, weights register-resident (96 VGPR).

#define Bsz   2048
#define Tlen  256
#define Fdim  64
#define Hdim  128
#define ROWS  8
#define NTH   512
#define TILE_E 512            // elems per kt tile (64 lanes x 8)
#define NKT   6               // kt 0,1 = x (K 0..63), kt 2..5 = h (K 64..191)
#define BUF_E (NKT * TILE_E)  // 3072 bf16 = 6 KB per buffer

using bf16x8 = __attribute__((ext_vector_type(8))) __bf16;
using f32x4  = __attribute__((ext_vector_type(4))) float;

__device__ __forceinline__ float fast_rcp(float x) {
#if __has_builtin(__builtin_amdgcn_rcpf)
    return __builtin_amdgcn_rcpf(x);
#else
    return 1.0f / x;
#endif
}
__device__ __forceinline__ float fast_exp2(float x) {
#if __has_builtin(__builtin_amdgcn_exp2f)
    return __builtin_amdgcn_exp2f(x);
#else
    return exp2f(x);
#endif
}
__device__ __forceinline__ float fsig(float x) {
    return fast_rcp(1.0f + fast_exp2(-1.4426950408889634f * x));
}
__device__ __forceinline__ float ftanh(float x) {
    float e = fast_exp2(-2.8853900817779268f * x);   // exp(-2x)
    return (1.0f - e) * fast_rcp(1.0f + e);
}

__device__ __forceinline__ bf16x8 cvt8(float4 a, float4 b) {
    bf16x8 r;
    r[0]=(__bf16)a.x; r[1]=(__bf16)a.y; r[2]=(__bf16)a.z; r[3]=(__bf16)a.w;
    r[4]=(__bf16)b.x; r[5]=(__bf16)b.y; r[6]=(__bf16)b.z; r[7]=(__bf16)b.w;
    return r;
}

// frag-order elem index for logical A[frag_row][k]
__device__ __forceinline__ int frag_elem(int row, int k) {
    return (k >> 5) * TILE_E + ((((k >> 3) & 3) * 16 + row) * 8) + (k & 7);
}

__global__ __launch_bounds__(NTH, 2)
void lstm_fused(const float* __restrict__ x,
                const float* __restrict__ W_ih,
                const float* __restrict__ W_hh,
                const float* __restrict__ b_ih,
                const float* __restrict__ b_hh,
                const float* __restrict__ W1,
                const float* __restrict__ b1,
                const float* __restrict__ W2,
                const float* __restrict__ b2,
                float* __restrict__ out)
{
    __shared__ __bf16 Abuf[2][BUF_E];       // 12 KB, fragment-order A operand
    __shared__ float  hlast[ROWS * Hdim];   // 4 KB fp32 h_T for head
    __shared__ float  zbuf[ROWS * 32];

    const int tid  = threadIdx.x;
    const int w    = tid >> 6;
    const int lane = tid & 63;
    const int quad = lane >> 4;
    const int l16  = lane & 15;
    const int b0   = blockIdx.x * ROWS;
    const bool hiq = (quad >= 2);           // selects acc elems {2,3} vs {0,1}

    // ---- weights, register-resident: x-part (2 kt) + h-part (4 kt) ----
    // lane holds B[k = kt*32 + quad*8 + j][n = g*128 + w*16 + l16]
    bf16x8 bwx[2][4], bwh[4][4];
    #pragma unroll
    for (int kt = 0; kt < NKT; ++kt) {
        const int k0 = kt * 32 + quad * 8;
        #pragma unroll
        for (int g = 0; g < 4; ++g) {
            const int n = g * Hdim + w * 16 + l16;
            const float* p = (kt < 2) ? (W_ih + (size_t)n * Fdim + k0)
                                      : (W_hh + (size_t)n * Hdim + (k0 - Fdim));
            float4 lo = *(const float4*)p;
            float4 hi = *(const float4*)(p + 4);
            bf16x8 r = cvt8(lo, hi);
            if (kt < 2) bwx[kt][g] = r; else bwh[kt - 2][g] = r;
        }
    }
    float biasv[4];
    #pragma unroll
    for (int g = 0; g < 4; ++g) {
        const int n = g * Hdim + w * 16 + l16;
        biasv[g] = b_ih[n] + b_hh[n];
    }

    // ---- x staging: threads 0..255 -> (row = tid&7, feat pair fp) ----
    // value written to frag rows row AND row+8 (dup-on-write, r5-proven)
    const bool sx_on  = tid < 256;
    const int  sx_row = tid & 7;
    const int  sx_fp  = (tid >> 3) & 31;
    const int  f0     = 2 * sx_fp;
    const float* xrp  = x + (size_t)(b0 + sx_row) * (Tlen * Fdim) + f0;
    const int sx_e0 = frag_elem(sx_row,     f0);   // f0 even -> 4B aligned
    const int sx_e1 = frag_elem(sx_row + 8, f0);

    // ---- elementwise cells (r5 mapping): 2 real cells/lane ----
    const int r0  = (quad >> 1) * 2;
    const int brb = (quad & 1) * 4 + r0;     // batch rows brb, brb+1
    const int hc  = 16 * w + l16;            // H-col 0..127
    const int h_e0a = frag_elem(brb,         Fdim + hc);
    const int h_e0b = frag_elem(brb + 8,     Fdim + hc);
    const int h_e1a = frag_elem(brb + 1,     Fdim + hc);
    const int h_e1b = frag_elem(brb + 1 + 8, Fdim + hc);

    // ---- init: zero buf0 (h0 = 0), stage x(1)->buf0, prefetch x(2),x(3) ----
    #pragma unroll
    for (int i = 0; i < BUF_E / NTH; ++i)
        Abuf[0][tid + i * NTH] = (__bf16)0.0f;
    __syncthreads();
    float2 xpA = make_float2(0.f, 0.f);      // staged at even t (holds x(t+2))
    float2 xpB = make_float2(0.f, 0.f);      // staged at odd  t
    if (sx_on) {
        float2 v1 = *(const float2*)(xrp + Fdim);     // x(1) -> buf0 x-slots
        __bf16 a1[2] = {(__bf16)v1.x, (__bf16)v1.y};
        *(uint*)&Abuf[0][sx_e0] = *(uint*)a1;
        *(uint*)&Abuf[0][sx_e1] = *(uint*)a1;
        xpA = *(const float2*)(xrp + 2 * Fdim);       // x(2), staged at t=0
        xpB = *(const float2*)(xrp + 3 * Fdim);       // x(3), staged at t=1
    }
    // xacc(0) = bias + x(0) W_ih^T, x(0) frags loaded directly from global:
    // A[row=l16][k=quad*8+j (kt0) / 32+quad*8+j (kt1)], row dup via l16&7
    f32x4 xacc[4];
    {
        const float* x0p = x + (size_t)(b0 + (l16 & 7)) * (Tlen * Fdim) + quad * 8;
        float4 a0 = *(const float4*)(x0p);
        float4 a1 = *(const float4*)(x0p + 4);
        float4 a2 = *(const float4*)(x0p + 32);
        float4 a3 = *(const float4*)(x0p + 36);
        bf16x8 xi0 = cvt8(a0, a1), xi1 = cvt8(a2, a3);
        #pragma unroll
        for (int g = 0; g < 4; ++g) {
            xacc[g] = (f32x4){biasv[g], biasv[g], biasv[g], biasv[g]};
            xacc[g] = __builtin_amdgcn_mfma_f32_16x16x32_bf16(xi0, bwx[0][g], xacc[g], 0, 0, 0);
            xacc[g] = __builtin_amdgcn_mfma_f32_16x16x32_bf16(xi1, bwx[1][g], xacc[g], 0, 0, 0);
        }
    }
    __syncthreads();

    float cc0 = 0.0f, cc1 = 0.0f;

    // One step. rb/wbf are compile-time-known buffers (x2 unroll below).
    // xstage holds x(t+2) on entry; we consume it late and refill with
    // x(t+4) issued EARLY -> the global load has ~2 full steps of shadow and
    // is NOT drained at the barrier (raw s_barrier, lgkmcnt-only wait).
    auto step = [&](int t, const __bf16* __restrict__ rb,
                    __bf16* __restrict__ wbf, float2& xstage) {
        // h(t-1) fragments: 4x conflict-free ds_read_b128 at lane*16B
        bf16x8 hf[4];
        #pragma unroll
        for (int kt = 0; kt < 4; ++kt)
            hf[kt] = *(const bf16x8*)&rb[(2 + kt) * TILE_E + lane * 8];
        // x(t+1) fragments (staged 2 steps ago; consumed AFTER elementwise)
        bf16x8 xf0 = *(const bf16x8*)&rb[lane * 8];
        bf16x8 xf1 = *(const bf16x8*)&rb[TILE_E + lane * 8];

        // grab the completed x(t+2) value, then issue the x(t+4) prefetch
        // early -- it stays in flight across the next barrier(s).
        float2 xcur = xstage;
        if (sx_on && (t + 4) < Tlen)
            xstage = *(const float2*)(xrp + (size_t)(t + 4) * Fdim);

        // gates(t) = xacc(t) + h-part: 16 MFMAs; xacc folded in as C operand
        f32x4 acc[4];
        #pragma unroll
        for (int g = 0; g < 4; ++g)
            acc[g] = __builtin_amdgcn_mfma_f32_16x16x32_bf16(hf[0], bwh[0][g], xacc[g], 0, 0, 0);
        #pragma unroll
        for (int kt = 1; kt < 4; ++kt) {
            #pragma unroll
            for (int g = 0; g < 4; ++g)
                acc[g] = __builtin_amdgcn_mfma_f32_16x16x32_bf16(hf[kt], bwh[kt][g], acc[g], 0, 0, 0);
        }

        // elementwise: 2 cells/lane, compile-time extracts (hiq selects)
        {
            float iv = fsig (hiq ? acc[0][2] : acc[0][0]);
            float fv = fsig (hiq ? acc[1][2] : acc[1][0]);
            float gv = ftanh(hiq ? acc[2][2] : acc[2][0]);
            float ov = fsig (hiq ? acc[3][2] : acc[3][0]);
            cc0 = fv * cc0 + iv * gv;
            float h = ov * ftanh(cc0);
            __bf16 hb = (__bf16)h;
            wbf[h_e0a] = hb;
            wbf[h_e0b] = hb;
            if (t == Tlen - 1) hlast[brb * Hdim + hc] = h;
        }
        {
            float iv = fsig (hiq ? acc[0][3] : acc[0][1]);
            float fv = fsig (hiq ? acc[1][3] : acc[1][1]);
            float gv = ftanh(hiq ? acc[2][3] : acc[2][1]);
            float ov = fsig (hiq ? acc[3][3] : acc[3][1]);
            cc1 = fv * cc1 + iv * gv;
            float h = ov * ftanh(cc1);
            __bf16 hb = (__bf16)h;
            wbf[h_e1a] = hb;
            wbf[h_e1b] = hb;
            if (t == Tlen - 1) hlast[(brb + 1) * Hdim + hc] = h;
        }

        // xacc(t+1) = bias + x(t+1) W_ih^T  -- barrier-skew shadow
        if ((t + 1) < Tlen) {
            #pragma unroll
            for (int g = 0; g < 4; ++g) {
                xacc[g] = (f32x4){biasv[g], biasv[g], biasv[g], biasv[g]};
                xacc[g] = __builtin_amdgcn_mfma_f32_16x16x32_bf16(xf0, bwx[0][g], xacc[g], 0, 0, 0);
                xacc[g] = __builtin_amdgcn_mfma_f32_16x16x32_bf16(xf1, bwx[1][g], xacc[g], 0, 0, 0);
            }
        }

        // stage x(t+2) (held in xcur) into the write buffer, both copies
        if (sx_on && (t + 2) < Tlen) {
            __bf16 xa[2] = {(__bf16)xcur.x, (__bf16)xcur.y};
            *(uint*)&wbf[sx_e0] = *(uint*)xa;
            *(uint*)&wbf[sx_e1] = *(uint*)xa;
        }

        // non-draining barrier: LDS must be visible (lgkmcnt 0), but global
        // prefetch loads stay in flight (NO vmcnt drain -- this is the fix).
        asm volatile("s_waitcnt lgkmcnt(0)" ::: "memory");
        __builtin_amdgcn_s_barrier();
        __builtin_amdgcn_sched_barrier(0);
    };

    for (int t = 0; t < Tlen; t += 2) {
        step(t,     Abuf[0], Abuf[1], xpA);
        step(t + 1, Abuf[1], Abuf[0], xpB);
    }

    // ---- head: z = relu(h @ W1^T + b1); out = sigmoid(z @ W2^T + b2) ----
    // (final loop barrier drained lgkmcnt and synced all waves: hlast is safe)
    if (tid < ROWS * 32) {
        const int b = tid >> 5, n = tid & 31;
        const float4* w4 = (const float4*)(W1 + n * Hdim);
        const float4* h4 = (const float4*)(hlast + b * Hdim);
        float s = b1[n];
        #pragma unroll
        for (int kk = 0; kk < Hdim / 4; ++kk) {
            float4 wv = w4[kk];
            float4 hv = h4[kk];
            s += wv.x * hv.x + wv.y * hv.y + wv.z * hv.z + wv.w * hv.w;
        }
        zbuf[b * 32 + n] = fmaxf(s, 0.0f);
    }
    __syncthreads();
    if (tid < ROWS) {
        float s = b2[0];
        #pragma unroll
        for (int n = 0; n < 32; ++n) s += zbuf[tid * 32 + n] * W2[n];
        out[b0 + tid] = fsig(s);
    }
}

extern "C" void kernel_launch(void* const* d_in, const int* in_sizes, int n_in,
                              void* d_out, int out_size, void* d_ws, size_t ws_size,
                              hipStream_t stream) {
    const float* x    = (const float*)d_in[0];
    const float* W_ih = (const float*)d_in[1];
    const float* W_hh = (const float*)d_in[2];
    const float* b_ih = (const float*)d_in[3];
    const float* b_hh = (const float*)d_in[4];
    const float* W1   = (const float*)d_in[5];
    const float* b1   = (const float*)d_in[6];
    const float* W2   = (const float*)d_in[7];
    const float* b2   = (const float*)d_in[8];
    float* out = (float*)d_out;

    dim3 grid(Bsz / ROWS), block(NTH);
    lstm_fused<<<grid, block, 0, stream>>>(x, W_ih, W_hh, b_ih, b_hh, W1, b1, W2, b2, out);
}

// Round 2
// 342.860 us; speedup vs baseline: 1.0679x; 1.0023x over previous
//
#include <hip/hip_runtime.h>

// Round 9: r8 (225us rocprof) + issue-order overlap + rcp-fused cell math.
// Counters showed MfmaUtil(44% pipe) + VALUBusy(48%) ~= 92% of step time:
// the pipes are SERIALIZED. Fixes:
//  (a) x-part MFMAs (xacc for t+1) + x staging moved BEFORE elementwise,
//      pinned by sched_barrier(0): their pipe time drains under the
//      elementwise VALU phase instead of being exposed before the barrier.
//      Bias pre-splatted to f32x4 regs used directly as MFMA C-in (kills
//      16 v_movs/step).
//  (b) elementwise rewritten over common denominators: 5 rcp/cell -> 2
//      (c' = [c*b*d + a*(1-eg)]*rcp(a*b*d); h = (1-ec)*rcp(u*v)).
//      Trans ops were ~2/3 of the VALU phase (quarter-rate pipe).
// Everything else = r8: 256x512, ROWS=8, dup-on-write M=16, weights in
// 96 VGPRs, non-draining barrier (lgkmcnt-only), 2-step x prefetch.

#define Bsz   2048
#define Tlen  256
#define Fdim  64
#define Hdim  128
#define ROWS  8
#define NTH   512
#define TILE_E 512            // elems per kt tile (64 lanes x 8)
#define NKT   6               // kt 0,1 = x (K 0..63), kt 2..5 = h (K 64..191)
#define BUF_E (NKT * TILE_E)  // 3072 bf16 = 6 KB per buffer

using bf16x8 = __attribute__((ext_vector_type(8))) __bf16;
using f32x4  = __attribute__((ext_vector_type(4))) float;

__device__ __forceinline__ float fast_rcp(float x) {
#if __has_builtin(__builtin_amdgcn_rcpf)
    return __builtin_amdgcn_rcpf(x);
#else
    return 1.0f / x;
#endif
}
__device__ __forceinline__ float fast_exp2(float x) {
#if __has_builtin(__builtin_amdgcn_exp2f)
    return __builtin_amdgcn_exp2f(x);
#else
    return exp2f(x);
#endif
}
#define LOG2E  1.4426950408889634f
#define LOG2E2 2.8853900817779268f

__device__ __forceinline__ bf16x8 cvt8(float4 a, float4 b) {
    bf16x8 r;
    r[0]=(__bf16)a.x; r[1]=(__bf16)a.y; r[2]=(__bf16)a.z; r[3]=(__bf16)a.w;
    r[4]=(__bf16)b.x; r[5]=(__bf16)b.y; r[6]=(__bf16)b.z; r[7]=(__bf16)b.w;
    return r;
}

// frag-order elem index for logical A[frag_row][k]
__device__ __forceinline__ int frag_elem(int row, int k) {
    return (k >> 5) * TILE_E + ((((k >> 3) & 3) * 16 + row) * 8) + (k & 7);
}

__global__ __launch_bounds__(NTH, 2)
void lstm_fused(const float* __restrict__ x,
                const float* __restrict__ W_ih,
                const float* __restrict__ W_hh,
                const float* __restrict__ b_ih,
                const float* __restrict__ b_hh,
                const float* __restrict__ W1,
                const float* __restrict__ b1,
                const float* __restrict__ W2,
                const float* __restrict__ b2,
                float* __restrict__ out)
{
    __shared__ __bf16 Abuf[2][BUF_E];       // 12 KB, fragment-order A operand
    __shared__ float  hlast[ROWS * Hdim];   // 4 KB fp32 h_T for head
    __shared__ float  zbuf[ROWS * 32];

    const int tid  = threadIdx.x;
    const int w    = tid >> 6;
    const int lane = tid & 63;
    const int quad = lane >> 4;
    const int l16  = lane & 15;
    const int b0   = blockIdx.x * ROWS;
    const bool hiq = (quad >= 2);           // selects acc elems {2,3} vs {0,1}

    // ---- weights, register-resident: x-part (2 kt) + h-part (4 kt) ----
    // lane holds B[k = kt*32 + quad*8 + j][n = g*128 + w*16 + l16]
    bf16x8 bwx[2][4], bwh[4][4];
    #pragma unroll
    for (int kt = 0; kt < NKT; ++kt) {
        const int k0 = kt * 32 + quad * 8;
        #pragma unroll
        for (int g = 0; g < 4; ++g) {
            const int n = g * Hdim + w * 16 + l16;
            const float* p = (kt < 2) ? (W_ih + (size_t)n * Fdim + k0)
                                      : (W_hh + (size_t)n * Hdim + (k0 - Fdim));
            float4 lo = *(const float4*)p;
            float4 hi = *(const float4*)(p + 4);
            bf16x8 r = cvt8(lo, hi);
            if (kt < 2) bwx[kt][g] = r; else bwh[kt - 2][g] = r;
        }
    }
    // bias pre-splatted into f32x4 regs; used directly as MFMA C-in (D!=C,
    // so no per-step copies are needed).
    f32x4 biasf[4];
    #pragma unroll
    for (int g = 0; g < 4; ++g) {
        const int n = g * Hdim + w * 16 + l16;
        const float bv = b_ih[n] + b_hh[n];
        biasf[g] = (f32x4){bv, bv, bv, bv};
    }

    // ---- x staging: threads 0..255 -> (row = tid&7, feat pair fp) ----
    // value written to frag rows row AND row+8 (dup-on-write, r5-proven)
    const bool sx_on  = tid < 256;
    const int  sx_row = tid & 7;
    const int  sx_fp  = (tid >> 3) & 31;
    const int  f0     = 2 * sx_fp;
    const float* xrp  = x + (size_t)(b0 + sx_row) * (Tlen * Fdim) + f0;
    const int sx_e0 = frag_elem(sx_row,     f0);   // f0 even -> 4B aligned
    const int sx_e1 = frag_elem(sx_row + 8, f0);

    // ---- elementwise cells (r5 mapping): 2 real cells/lane ----
    const int r0  = (quad >> 1) * 2;
    const int brb = (quad & 1) * 4 + r0;     // batch rows brb, brb+1
    const int hc  = 16 * w + l16;            // H-col 0..127
    const int h_e0a = frag_elem(brb,         Fdim + hc);
    const int h_e0b = frag_elem(brb + 8,     Fdim + hc);
    const int h_e1a = frag_elem(brb + 1,     Fdim + hc);
    const int h_e1b = frag_elem(brb + 1 + 8, Fdim + hc);

    // ---- init: zero buf0 (h0 = 0), stage x(1)->buf0, prefetch x(2),x(3) ----
    #pragma unroll
    for (int i = 0; i < BUF_E / NTH; ++i)
        Abuf[0][tid + i * NTH] = (__bf16)0.0f;
    __syncthreads();
    float2 xpA = make_float2(0.f, 0.f);      // staged at even t (holds x(t+2))
    float2 xpB = make_float2(0.f, 0.f);      // staged at odd  t
    if (sx_on) {
        float2 v1 = *(const float2*)(xrp + Fdim);     // x(1) -> buf0 x-slots
        __bf16 a1[2] = {(__bf16)v1.x, (__bf16)v1.y};
        *(uint*)&Abuf[0][sx_e0] = *(uint*)a1;
        *(uint*)&Abuf[0][sx_e1] = *(uint*)a1;
        xpA = *(const float2*)(xrp + 2 * Fdim);       // x(2), staged at t=0
        xpB = *(const float2*)(xrp + 3 * Fdim);       // x(3), staged at t=1
    }
    // xacc(0) = bias + x(0) W_ih^T, x(0) frags loaded directly from global:
    // A[row=l16][k=quad*8+j (kt0) / 32+quad*8+j (kt1)], row dup via l16&7
    f32x4 xacc[4];
    {
        const float* x0p = x + (size_t)(b0 + (l16 & 7)) * (Tlen * Fdim) + quad * 8;
        float4 a0 = *(const float4*)(x0p);
        float4 a1 = *(const float4*)(x0p + 4);
        float4 a2 = *(const float4*)(x0p + 32);
        float4 a3 = *(const float4*)(x0p + 36);
        bf16x8 xi0 = cvt8(a0, a1), xi1 = cvt8(a2, a3);
        #pragma unroll
        for (int g = 0; g < 4; ++g) {
            f32x4 tmp = __builtin_amdgcn_mfma_f32_16x16x32_bf16(xi0, bwx[0][g], biasf[g], 0, 0, 0);
            xacc[g]   = __builtin_amdgcn_mfma_f32_16x16x32_bf16(xi1, bwx[1][g], tmp, 0, 0, 0);
        }
    }
    __syncthreads();

    float cc0 = 0.0f, cc1 = 0.0f;

    // One step. Program order is the point: [ds_reads | prefetch issue |
    // 16 h-MFMA | 8 x-MFMA | x staging | sched_barrier | elementwise |
    // h-write | lgkmcnt | s_barrier]. In-order issue puts all MFMA pipe
    // work in flight BEFORE the elementwise VALU phase, so the pipes
    // overlap instead of serializing.
    auto step = [&](int t, const __bf16* __restrict__ rb,
                    __bf16* __restrict__ wbf, float2& xstage) {
        // h(t-1) fragments: 4x conflict-free ds_read_b128 at lane*16B
        bf16x8 hf[4];
        #pragma unroll
        for (int kt = 0; kt < 4; ++kt)
            hf[kt] = *(const bf16x8*)&rb[(2 + kt) * TILE_E + lane * 8];
        // x(t+1) fragments (staged 2 steps ago)
        bf16x8 xf0 = *(const bf16x8*)&rb[lane * 8];
        bf16x8 xf1 = *(const bf16x8*)&rb[TILE_E + lane * 8];

        // grab the completed x(t+2) value, then issue the x(t+4) prefetch
        // early -- it stays in flight across the barriers (no vmcnt drain).
        float2 xcur = xstage;
        if (sx_on && (t + 4) < Tlen)
            xstage = *(const float2*)(xrp + (size_t)(t + 4) * Fdim);

        // gates(t) = xacc(t) + h-part: 16 MFMAs; xacc folded in as C operand
        f32x4 acc[4];
        #pragma unroll
        for (int g = 0; g < 4; ++g)
            acc[g] = __builtin_amdgcn_mfma_f32_16x16x32_bf16(hf[0], bwh[0][g], xacc[g], 0, 0, 0);
        #pragma unroll
        for (int kt = 1; kt < 4; ++kt) {
            #pragma unroll
            for (int g = 0; g < 4; ++g)
                acc[g] = __builtin_amdgcn_mfma_f32_16x16x32_bf16(hf[kt], bwh[kt][g], acc[g], 0, 0, 0);
        }

        // xacc(t+1) = bias + x(t+1) W_ih^T -- issued NOW so the MFMA pipe
        // drains it under the elementwise VALU phase (results needed only
        // next step; zero exposed latency).
        if ((t + 1) < Tlen) {
            #pragma unroll
            for (int g = 0; g < 4; ++g) {
                f32x4 tmp = __builtin_amdgcn_mfma_f32_16x16x32_bf16(xf0, bwx[0][g], biasf[g], 0, 0, 0);
                xacc[g]   = __builtin_amdgcn_mfma_f32_16x16x32_bf16(xf1, bwx[1][g], tmp, 0, 0, 0);
            }
        }

        // stage x(t+2) (held in xcur) into the write buffer, both copies --
        // independent of acc, issue before the VALU phase.
        if (sx_on && (t + 2) < Tlen) {
            __bf16 xa[2] = {(__bf16)xcur.x, (__bf16)xcur.y};
            *(uint*)&wbf[sx_e0] = *(uint*)xa;
            *(uint*)&wbf[sx_e1] = *(uint*)xa;
        }

        // pin: everything above is issued before the elementwise phase.
        __builtin_amdgcn_sched_barrier(0);

        // elementwise: 2 cells/lane, rcp-fused gate math.
        // c' = sig(f)*c + sig(i)*tanh(g)
        //    = [c*(1+ei)(1+eg) + (1+ef)(1-eg)] * rcp((1+ef)(1+ei)(1+eg))
        // h  = sig(o)*tanh(c') = (1-ec) * rcp((1+eo)(1+ec))
        {
            float gi = hiq ? acc[0][2] : acc[0][0];
            float gf = hiq ? acc[1][2] : acc[1][0];
            float gg = hiq ? acc[2][2] : acc[2][0];
            float go = hiq ? acc[3][2] : acc[3][0];
            float ei = fast_exp2(-LOG2E  * gi);
            float ef = fast_exp2(-LOG2E  * gf);
            float eg = fast_exp2(-LOG2E2 * gg);
            float eo = fast_exp2(-LOG2E  * go);
            float a = 1.0f + ef, b = 1.0f + ei, d = 1.0f + eg;
            float bd  = b * d;
            float num = cc0 * bd + a * (1.0f - eg);
            cc0 = num * fast_rcp(a * bd);
            float ec = fast_exp2(-LOG2E2 * cc0);
            float h  = (1.0f - ec) * fast_rcp((1.0f + eo) * (1.0f + ec));
            __bf16 hb = (__bf16)h;
            wbf[h_e0a] = hb;
            wbf[h_e0b] = hb;
            if (t == Tlen - 1) hlast[brb * Hdim + hc] = h;
        }
        {
            float gi = hiq ? acc[0][3] : acc[0][1];
            float gf = hiq ? acc[1][3] : acc[1][1];
            float gg = hiq ? acc[2][3] : acc[2][1];
            float go = hiq ? acc[3][3] : acc[3][1];
            float ei = fast_exp2(-LOG2E  * gi);
            float ef = fast_exp2(-LOG2E  * gf);
            float eg = fast_exp2(-LOG2E2 * gg);
            float eo = fast_exp2(-LOG2E  * go);
            float a = 1.0f + ef, b = 1.0f + ei, d = 1.0f + eg;
            float bd  = b * d;
            float num = cc1 * bd + a * (1.0f - eg);
            cc1 = num * fast_rcp(a * bd);
            float ec = fast_exp2(-LOG2E2 * cc1);
            float h  = (1.0f - ec) * fast_rcp((1.0f + eo) * (1.0f + ec));
            __bf16 hb = (__bf16)h;
            wbf[h_e1a] = hb;
            wbf[h_e1b] = hb;
            if (t == Tlen - 1) hlast[(brb + 1) * Hdim + hc] = h;
        }

        // non-draining barrier: LDS must be visible (lgkmcnt 0), but global
        // prefetch loads stay in flight (NO vmcnt drain).
        asm volatile("s_waitcnt lgkmcnt(0)" ::: "memory");
        __builtin_amdgcn_s_barrier();
        __builtin_amdgcn_sched_barrier(0);
    };

    for (int t = 0; t < Tlen; t += 2) {
        step(t,     Abuf[0], Abuf[1], xpA);
        step(t + 1, Abuf[1], Abuf[0], xpB);
    }

    // ---- head: z = relu(h @ W1^T + b1); out = sigmoid(z @ W2^T + b2) ----
    // (final loop barrier drained lgkmcnt and synced all waves: hlast safe)
    if (tid < ROWS * 32) {
        const int b = tid >> 5, n = tid & 31;
        const float4* w4 = (const float4*)(W1 + n * Hdim);
        const float4* h4 = (const float4*)(hlast + b * Hdim);
        float s = b1[n];
        #pragma unroll
        for (int kk = 0; kk < Hdim / 4; ++kk) {
            float4 wv = w4[kk];
            float4 hv = h4[kk];
            s += wv.x * hv.x + wv.y * hv.y + wv.z * hv.z + wv.w * hv.w;
        }
        zbuf[b * 32 + n] = fmaxf(s, 0.0f);
    }
    __syncthreads();
    if (tid < ROWS) {
        float s = b2[0];
        #pragma unroll
        for (int n = 0; n < 32; ++n) s += zbuf[tid * 32 + n] * W2[n];
        float e = fast_exp2(-LOG2E * s);
        out[b0 + tid] = fast_rcp(1.0f + e);
    }
}

extern "C" void kernel_launch(void* const* d_in, const int* in_sizes, int n_in,
                              void* d_out, int out_size, void* d_ws, size_t ws_size,
                              hipStream_t stream) {
    const float* x    = (const float*)d_in[0];
    const float* W_ih = (const float*)d_in[1];
    const float* W_hh = (const float*)d_in[2];
    const float* b_ih = (const float*)d_in[3];
    const float* b_hh = (const float*)d_in[4];
    const float* W1   = (const float*)d_in[5];
    const float* b1   = (const float*)d_in[6];
    const float* W2   = (const float*)d_in[7];
    const float* b2   = (const float*)d_in[8];
    float* out = (float*)d_out;

    dim3 grid(Bsz / ROWS), block(NTH);
    lstm_fused<<<grid, block, 0, stream>>>(x, W_ih, W_hh, b_ih, b_hh, W1, b1, W2, b2, out);
}